// Round 9
// baseline (890.211 us; speedup 1.0000x reference)
//
#include <hip/hip_runtime.h>
#include <math.h>

#define LEAKY(v) ((v) > 0.f ? (v) : 0.01f * (v))

typedef float f2v __attribute__((ext_vector_type(2)));

// ------------------------------------------------- manual grid barrier ----
// Device-scope sense barrier. cnt/gen zeroed by prep_k each launch.
// Bounded spin (~1M iters) as a deadlock fuse: if co-residency ever fails
// we get a wrong answer + diagnosable bench, not a container timeout.
__device__ __forceinline__ void gridbar(unsigned* cnt, unsigned* gen, unsigned nb) {
  __syncthreads();
  if (threadIdx.x == 0) {
    __threadfence();
    unsigned g = __hip_atomic_load(gen, __ATOMIC_ACQUIRE, __HIP_MEMORY_SCOPE_AGENT);
    unsigned a = __hip_atomic_fetch_add(cnt, 1u, __ATOMIC_ACQ_REL, __HIP_MEMORY_SCOPE_AGENT) + 1;
    if (a == nb) {
      __hip_atomic_store(cnt, 0u, __ATOMIC_RELAXED, __HIP_MEMORY_SCOPE_AGENT);
      __hip_atomic_store(gen, g + 1u, __ATOMIC_RELEASE, __HIP_MEMORY_SCOPE_AGENT);
    } else {
      int guard = 1 << 20;
      while (__hip_atomic_load(gen, __ATOMIC_ACQUIRE, __HIP_MEMORY_SCOPE_AGENT) == g && --guard) {}
    }
    __threadfence();
  }
  __syncthreads();
}

// ------------------------------------------------------------------ gates ----
__device__ __forceinline__ void cmm2(const float* Ar, const float* Ai,
                                     const float* Br, const float* Bi,
                                     float* Cr, float* Ci) {
#pragma unroll
  for (int r = 0; r < 2; r++)
#pragma unroll
    for (int c = 0; c < 2; c++) {
      float xr = 0.f, xi = 0.f;
#pragma unroll
      for (int k = 0; k < 2; k++) {
        float ar = Ar[r*2+k], ai = Ai[r*2+k];
        float br = Br[k*2+c], bi = Bi[k*2+c];
        xr += ar*br - ai*bi;
        xi += ar*bi + ai*br;
      }
      Cr[r*2+c] = xr; Ci[r*2+c] = xi;
    }
}

// 60 fused gates + zero stats (1280 floats) + zero barrier words.
__global__ __launch_bounds__(256) void prep_k(const float* __restrict__ qw,
                                              float* __restrict__ gates,
                                              float* __restrict__ stats) {
  int t = threadIdx.x;
  for (int i = t; i < 1288; i += 256) stats[i] = 0.f;   // stats + sync words
  if (t < 60) {
    float a = qw[t*3+0], b = qw[t*3+1], c = qw[t*3+2];
    float ca = cosf(0.5f*a), sa = sinf(0.5f*a);
    float cb = cosf(0.5f*b), sb = sinf(0.5f*b);
    float RXr[4] = {ca, 0.f, 0.f, ca};
    float RXi[4] = {0.f, -sa, -sa, 0.f};
    float RYr[4] = {cb, -sb, sb, cb};
    float RYi[4] = {0.f, 0.f, 0.f, 0.f};
    float hc = 0.5f*c;
    float RZr[4] = {cosf(hc), 0.f, 0.f, cosf(hc)};
    float RZi[4] = {-sinf(hc), 0.f, 0.f, sinf(hc)};
    float epr = cosf(b), epi = sinf(b);
    float edr = cosf(c), edi = sinf(c);
    float eer = epr*edr - epi*edi, eei = epr*edi + epi*edr;
    float U3r[4] = {ca, -edr*sa, epr*sa, eer*ca};
    float U3i[4] = {0.f, -edi*sa, epi*sa, eei*ca};
    float T1r[4],T1i[4],T2r[4],T2i[4],Gr[4],Gi[4];
    cmm2(RYr,RYi, RXr,RXi, T1r,T1i);
    cmm2(RZr,RZi, T1r,T1i, T2r,T2i);
    cmm2(U3r,U3i, T2r,T2i, Gr,Gi);
#pragma unroll
    for (int m = 0; m < 4; m++) {
      gates[t*8 + 2*m]     = Gr[m];
      gates[t*8 + 2*m + 1] = Gi[m];
    }
  }
}

// ------------------------------------------------------- gemm tile (device) ----
struct GemmLds {
  float As[64][65];
  float Bs[64][65];
  float sc1[256], sh1[256];
  float sc2[128], sh2[128];
};

// C[r][c] = sum_k pre(A)[r][k] * W[c][k] + bias[c]   (one 64x64 tile)
// pre(A)[r][k] = f1(A1[r*ld1+k]) + scale2 * f2(A2[r*ld2+k])
//   fi(v) = stats_i ? leaky(sc_i[k]*v + sh_i[k]) : v
// statsOut: per-column (sum, sumsq) atomics.
__device__ __forceinline__ void gemm_tile(
    GemmLds& L, int bx, int by,
    const float* __restrict__ A1, const float* __restrict__ st1,
    const float* __restrict__ g1, const float* __restrict__ be1, int ld1,
    const float* __restrict__ A2, const float* __restrict__ st2,
    const float* __restrict__ g2, const float* __restrict__ be2, int ld2,
    float scale2,
    const float* __restrict__ W, const float* __restrict__ bias,
    float* __restrict__ C, float* __restrict__ statsOut, int N, int K) {
  const int r0 = bx * 64;
  const int c0 = by * 64;
  const int tid = threadIdx.x;
  const int ty = tid >> 4, tx = tid & 15;
  const bool lk1 = (st1 != nullptr);
  const bool lk2 = (st2 != nullptr);
  for (int k = tid; k < K; k += 256) {
    if (lk1) {
      float mean = st1[2*k] * (1.f/4096.f);
      float var  = st1[2*k+1] * (1.f/4096.f) - mean*mean;
      float s = g1[k] * rsqrtf(var + 1e-5f);
      L.sc1[k] = s; L.sh1[k] = be1[k] - mean*s;
    } else { L.sc1[k] = 1.f; L.sh1[k] = 0.f; }
    if (A2 && k < 128) {
      if (lk2) {
        float mean = st2[2*k] * (1.f/4096.f);
        float var  = st2[2*k+1] * (1.f/4096.f) - mean*mean;
        float s = g2[k] * rsqrtf(var + 1e-5f);
        L.sc2[k] = s; L.sh2[k] = be2[k] - mean*s;
      } else { L.sc2[k] = 1.f; L.sh2[k] = 0.f; }
    }
  }
  __syncthreads();
  float acc[4][4] = {};
  for (int kc = 0; kc < K; kc += 64) {
#pragma unroll
    for (int i = 0; i < 16; i++) {
      int t = tid + 256*i;
      int lr = t >> 6, lk = t & 63;
      float av = 0.f, wv = 0.f;
      int k = kc + lk;
      if (k < K) {
        float v1 = A1[(size_t)(r0+lr)*ld1 + k];
        v1 = L.sc1[k]*v1 + L.sh1[k];
        if (lk1) v1 = LEAKY(v1);
        av = v1;
        if (A2) {
          float v2 = A2[(size_t)(r0+lr)*ld2 + k];
          v2 = L.sc2[k]*v2 + L.sh2[k];
          if (lk2) v2 = LEAKY(v2);
          av += scale2 * v2;
        }
        if (c0 + lr < N) wv = W[(size_t)(c0+lr)*K + k];
      }
      L.As[lr][lk] = av;
      L.Bs[lr][lk] = wv;
    }
    __syncthreads();
#pragma unroll 16
    for (int kk = 0; kk < 64; kk++) {
      float ar[4], wr[4];
#pragma unroll
      for (int i = 0; i < 4; i++) ar[i] = L.As[ty*4+i][kk];
#pragma unroll
      for (int j = 0; j < 4; j++) wr[j] = L.Bs[tx*4+j][kk];
#pragma unroll
      for (int i = 0; i < 4; i++)
#pragma unroll
        for (int j = 0; j < 4; j++)
          acc[i][j] = fmaf(ar[i], wr[j], acc[i][j]);
    }
    __syncthreads();
  }
  float bv[4];
#pragma unroll
  for (int j = 0; j < 4; j++) {
    int c = c0 + tx*4 + j;
    bv[j] = (c < N) ? bias[c] : 0.f;
  }
#pragma unroll
  for (int i = 0; i < 4; i++) {
    int r = r0 + ty*4 + i;
#pragma unroll
    for (int j = 0; j < 4; j++) {
      int c = c0 + tx*4 + j;
      if (c < N) C[(size_t)r*N + c] = acc[i][j] + bv[j];
    }
  }
  if (statsOut) {
    __syncthreads();
#pragma unroll
    for (int j = 0; j < 4; j++) {
      float s = 0.f, q = 0.f;
#pragma unroll
      for (int i = 0; i < 4; i++) {
        float v = acc[i][j] + bv[j];
        s += v; q += v*v;
      }
      L.As[ty][tx*4+j] = s;
      L.Bs[ty][tx*4+j] = q;
    }
    __syncthreads();
    if (tid < 64) {
      float s = 0.f, q = 0.f;
#pragma unroll
      for (int t = 0; t < 16; t++) { s += L.As[t][tid]; q += L.Bs[t][tid]; }
      int c = c0 + tid;
      if (c < N) {
        atomicAdd(&statsOut[2*c], s);
        atomicAdd(&statsOut[2*c+1], q);
      }
    }
    __syncthreads();
  }
}

// --------------------------------------------------------- fused pre-chain ----
struct PreArgs {
  const float *x, *Wsk, *bs, *W1, *b1, *g1, *be1, *W2, *b2, *g2, *be2,
              *W3, *b3, *g3, *be3, *Wp, *bp;
  float *STATS, *SKIP, *BUF1, *BUF2, *BUF3, *ZP;
  unsigned *SYNC;
};

__global__ __launch_bounds__(256) void fused_pre(PreArgs p) {
  __shared__ GemmLds L;
  const int bid = blockIdx.x;
  unsigned* cnt = p.SYNC;
  unsigned* gen = p.SYNC + 1;
  // S0: z1 = x@W1^T+b1 (jobs 0..255, stats->ST1); skip = x@Ws^T+bs (256..383)
  if (bid < 256)
    gemm_tile(L, bid % 64, bid / 64, p.x, nullptr,nullptr,nullptr, 64,
              nullptr,nullptr,nullptr,nullptr, 0, 0.f,
              p.W1, p.b1, p.BUF1, p.STATS, 256, 64);
  else {
    int js = bid - 256;
    gemm_tile(L, js % 64, js / 64, p.x, nullptr,nullptr,nullptr, 64,
              nullptr,nullptr,nullptr,nullptr, 0, 0.f,
              p.Wsk, p.bs, p.SKIP, nullptr, 128, 64);
  }
  gridbar(cnt, gen, 384);
  // S1: z2 = leakyBN1(z1)@W2^T+b2, stats->ST2 (128 jobs)
  if (bid < 128)
    gemm_tile(L, bid % 64, bid / 64, p.BUF1, p.STATS, p.g1, p.be1, 256,
              nullptr,nullptr,nullptr,nullptr, 0, 0.f,
              p.W2, p.b2, p.BUF2, p.STATS + 512, 128, 256);
  gridbar(cnt, gen, 384);
  // S2: z3 = leakyBN2(z2)@W3^T+b3, stats->ST3 (64 jobs)
  if (bid < 64)
    gemm_tile(L, bid, 0, p.BUF2, p.STATS + 512, p.g2, p.be2, 128,
              nullptr,nullptr,nullptr,nullptr, 0, 0.f,
              p.W3, p.b3, p.BUF3, p.STATS + 768, 64, 128);
  gridbar(cnt, gen, 384);
  // S3: zp = (leakyBN3(z3)+0.1*leakyBN1(z1[:, :64]))@Wp^T+bp (64 jobs)
  if (bid < 64)
    gemm_tile(L, bid, 0, p.BUF3, p.STATS + 768, p.g3, p.be3, 64,
              p.BUF1, p.STATS, p.g1, p.be1, 256, 0.1f,
              p.Wp, p.bp, p.ZP, nullptr, 12, 64);
}

// ----------------------------------------------------------- quantum sim ----
// (identical to round 4/7 — 238 us, VGPR 56, proven correct)
__device__ __forceinline__ int SWZi(int i) { return i ^ ((i >> 4) & 15); }
__device__ __forceinline__ int LINV_E(int i) {
  return i ^ ((i >> 1) & 0x7FF) ^ ((i & 1) ? 0xC00 : 0);
}
__device__ __forceinline__ int LINV_O(int i) {
  int hi = i & 0xAAA;
  return (i & 0x555) | ((hi ^ (hi << 6)) & 0xA80) | ((hi >> 6) & 0x2A);
}

template<int B>
__device__ __forceinline__ void gate16(f2v* a, const float* __restrict__ g) {
  const float g00r=g[0], g00i=g[1], g01r=g[2], g01i=g[3];
  const float g10r=g[4], g10i=g[5], g11r=g[6], g11i=g[7];
#pragma unroll
  for (int m = 0; m < 8; m++) {
    const int l0 = ((m >> B) << (B+1)) | (m & ((1<<B)-1));
    const int l1 = l0 | (1 << B);
    f2v A = a[l0], Bv = a[l1];
    f2v Ai; Ai.x = -A.y;  Ai.y = A.x;     // i*A
    f2v Bi; Bi.x = -Bv.y; Bi.y = Bv.x;    // i*B
    a[l0] = g00r*A + (g00i*Ai + (g01r*Bv + g01i*Bi));
    a[l1] = g10r*A + (g10i*Ai + (g11r*Bv + g11i*Bi));
  }
}

__global__ __launch_bounds__(256, 4) void quantum_k(const float* __restrict__ zpre,
                                                    const float* __restrict__ gates,
                                                    float* __restrict__ qout) {
  __shared__ f2v st[4096];                 // 32 KiB exactly
  float* stf = (float*)st;                 // aliased scratch (trig, reduction)
  const int tid = threadIdx.x, b = blockIdx.x;
  if (tid < 12) {
    float xp = tanhf(zpre[b*12 + tid]);
    float h = xp * 1.57079632679489662f;   // pi/2
    stf[tid] = cosf(h);
    stf[12 + tid] = sinf(h);
  }
  __syncthreads();
  float cs[12], sn[12];
#pragma unroll
  for (int q = 0; q < 12; q++) { cs[q] = stf[q]; sn[q] = stf[12+q]; }
  __syncthreads();                         // trig region reused by state below
  // Layout A: idx = (tid<<4)|l. idx bit bb <-> qubit 11-bb.
  f2v a[16];
  {
    float pre = 1.f;
#pragma unroll
    for (int q = 0; q < 8; q++) pre *= ((tid >> (7-q)) & 1) ? sn[q] : cs[q];
#pragma unroll
    for (int l = 0; l < 16; l++) {
      float v = pre;
      v *= (l & 8) ? sn[8]  : cs[8];
      v *= (l & 4) ? sn[9]  : cs[9];
      v *= (l & 2) ? sn[10] : cs[10];
      v *= (l & 1) ? sn[11] : cs[11];
      a[l].x = v; a[l].y = 0.f;
    }
  }
  // per-thread address bases (all accesses are base ^ const(l))
  const int mA    = tid & 15;
  const int baseA = (tid << 4) | mA;                 // layout A slots
  const int baseB = ((tid >> 4) << 8) | mA;          // layout B slots
  const int baseC = tid ^ ((tid >> 4) & 15);         // layout C slots
  const int gE    = SWZi(LINV_E(tid << 4));          // even-layer gather base
  const int gO    = SWZi(LINV_O(tid << 4));          // odd-layer gather base
  for (int layer = 0; layer < 5; layer++) {
    const float* gl = gates + layer * 96;
    gate16<3>(a, gl + 64); gate16<2>(a, gl + 72);    // qubits 8..11 (layout A)
    gate16<1>(a, gl + 80); gate16<0>(a, gl + 88);
#pragma unroll
    for (int l = 0; l < 16; l++) st[baseA ^ l] = a[l];
    __syncthreads();
#pragma unroll
    for (int l = 0; l < 16; l++) a[l] = st[baseB ^ ((l << 4) | l)];
    gate16<3>(a, gl + 32); gate16<2>(a, gl + 40);    // qubits 4..7 (layout B)
    gate16<1>(a, gl + 48); gate16<0>(a, gl + 56);
#pragma unroll
    for (int l = 0; l < 16; l++) st[baseB ^ ((l << 4) | l)] = a[l];
    __syncthreads();
#pragma unroll
    for (int l = 0; l < 16; l++) a[l] = st[baseC ^ (l << 8)];
    gate16<3>(a, gl +  0); gate16<2>(a, gl +  8);    // qubits 0..3 (layout C)
    gate16<1>(a, gl + 16); gate16<0>(a, gl + 24);
#pragma unroll
    for (int l = 0; l < 16; l++) st[baseC ^ (l << 8)] = a[l];
    __syncthreads();
    // CNOT chain: gather back to layout A, new[i] = old[Linv(i)]
    if ((layer & 1) == 0) {
#pragma unroll
      for (int l = 0; l < 16; l++) a[l] = st[gE ^ SWZi(LINV_E(l))];
    } else {
#pragma unroll
      for (int l = 0; l < 16; l++) a[l] = st[gO ^ SWZi(LINV_O(l))];
    }
    __syncthreads();
  }
  // Re-store post-CNOT state into layout-A slots for the X-measurement.
#pragma unroll
  for (int l = 0; l < 16; l++) st[baseA ^ l] = a[l];
  __syncthreads();
  // ---- measurement: 12 Z expectations + 6 X-type pair sums ----
  float pl[16], tot = 0.f;
#pragma unroll
  for (int l = 0; l < 16; l++) { pl[l] = a[l].x*a[l].x + a[l].y*a[l].y; tot += pl[l]; }
  float part[18];
#pragma unroll
  for (int q = 0; q < 8; q++) part[q] = ((tid >> (7-q)) & 1) ? -tot : tot;
#pragma unroll
  for (int q = 8; q < 12; q++) {
    const int bit = 11 - q;
    float s = 0.f;
#pragma unroll
    for (int l = 0; l < 16; l++) s += ((l >> bit) & 1) ? -pl[l] : pl[l];
    part[q] = s;
  }
#pragma unroll
  for (int q = 0; q < 6; q++) {
    const int bt = 7 - q;                  // qubit q <-> tid bit 7-q
    float s = 0.f;
    if (((tid >> bt) & 1) == 0) {
      const int tid2 = tid | (1 << bt);
      const int baseA2 = (tid2 << 4) | (tid2 & 15);
#pragma unroll
      for (int l = 0; l < 16; l++) {
        f2v bb = st[baseA2 ^ l];
        s += a[l].x*bb.x + a[l].y*bb.y;    // Re(conj(a0)*a1)
      }
    }
    part[12+q] = 2.f * s;
  }
  __syncthreads();                         // st reads done; reuse as scratch
#pragma unroll
  for (int j = 0; j < 18; j++) {
    float v = part[j];
#pragma unroll
    for (int m = 1; m < 64; m <<= 1) v += __shfl_xor(v, m);
    if ((tid & 63) == 0) stf[(tid >> 6)*18 + j] = v;
  }
  __syncthreads();
  if (tid < 18) qout[b*18 + tid] = stf[tid] + stf[18+tid] + stf[36+tid] + stf[54+tid];
}

// --------------------------------------------------------- fused post-chain ----
struct PostArgs {
  const float *QOUT, *Wq1, *bq1, *gq1, *beq1, *Wq2, *bq2, *gq2, *beq2,
              *SKIP, *Wo1, *bo1, *Wo2, *bo2;
  float *STATS, *BUF2, *BUF3, *out;
  unsigned *SYNC;
};

__global__ __launch_bounds__(256) void fused_post(PostArgs p) {
  __shared__ GemmLds L;
  const int bid = blockIdx.x, tid = threadIdx.x;
  unsigned* cnt = p.SYNC;
  unsigned* gen = p.SYNC + 1;
  // S0: zq1 = q_out@Wq1^T+bq1, stats->SQ1 (128 jobs)
  if (bid < 128)
    gemm_tile(L, bid % 64, bid / 64, p.QOUT, nullptr,nullptr,nullptr, 18,
              nullptr,nullptr,nullptr,nullptr, 0, 0.f,
              p.Wq1, p.bq1, p.BUF2, p.STATS + 896, 128, 18);
  gridbar(cnt, gen, 256);
  // S1: zq2 = (leakyBNq1(zq1)+skip)@Wq2^T+bq2, stats->SQ2 (64 jobs)
  if (bid < 64)
    gemm_tile(L, bid, 0, p.BUF2, p.STATS + 896, p.gq1, p.beq1, 128,
              p.SKIP, nullptr, nullptr, nullptr, 128, 1.0f,
              p.Wq2, p.bq2, p.BUF3, p.STATS + 1152, 64, 128);
  gridbar(cnt, gen, 256);
  // S2: out = leaky(leakyBNq2(zq2)@Wo1^T+bo1)@Wo2^T+bo2  (16 rows/block)
  if (tid < 64) {
    const float* SQ2 = p.STATS + 1152;
    float mean = SQ2[2*tid] * (1.f/4096.f);
    float var  = SQ2[2*tid+1] * (1.f/4096.f) - mean*mean;
    float s = p.gq2[tid] * rsqrtf(var + 1e-5f);
    L.sc2[tid] = s; L.sh2[tid] = p.beq2[tid] - mean*s;
  }
  __syncthreads();
#pragma unroll
  for (int rr = 0; rr < 2; rr++) {
    int row = bid*16 + rr*8 + (tid >> 5);
    int o = tid & 31;
    float acc = 0.f;
#pragma unroll 8
    for (int k = 0; k < 64; k++) {
      float v = L.sc2[k]*p.BUF3[(size_t)row*64 + k] + L.sh2[k];
      v = LEAKY(v);
      acc = fmaf(v, p.Wo1[o*64 + k], acc);
    }
    float h = acc + p.bo1[o];
    h = LEAKY(h);
    float v = h * p.Wo2[o];
#pragma unroll
    for (int m = 1; m < 32; m <<= 1) v += __shfl_xor(v, m);
    if (o == 0) p.out[row] = v + p.bo2[0];
  }
}

// --------------------------------------------------------------- launch ----
extern "C" void kernel_launch(void* const* d_in, const int* in_sizes, int n_in,
                              void* d_out, int out_size, void* d_ws, size_t ws_size,
                              hipStream_t stream) {
  (void)in_sizes; (void)n_in; (void)out_size; (void)ws_size;
  const float* x   = (const float*)d_in[0];
  const float* Wsk = (const float*)d_in[1];
  const float* bs  = (const float*)d_in[2];
  const float* W1  = (const float*)d_in[3];
  const float* b1  = (const float*)d_in[4];
  const float* g1  = (const float*)d_in[5];
  const float* be1 = (const float*)d_in[6];
  const float* W2  = (const float*)d_in[7];
  const float* b2  = (const float*)d_in[8];
  const float* g2  = (const float*)d_in[9];
  const float* be2 = (const float*)d_in[10];
  const float* W3  = (const float*)d_in[11];
  const float* b3  = (const float*)d_in[12];
  const float* g3  = (const float*)d_in[13];
  const float* be3 = (const float*)d_in[14];
  const float* Wp  = (const float*)d_in[15];
  const float* bp  = (const float*)d_in[16];
  const float* qw  = (const float*)d_in[17];
  const float* Wq1 = (const float*)d_in[18];
  const float* bq1 = (const float*)d_in[19];
  const float* gq1 = (const float*)d_in[20];
  const float* beq1= (const float*)d_in[21];
  const float* Wq2 = (const float*)d_in[22];
  const float* bq2 = (const float*)d_in[23];
  const float* gq2 = (const float*)d_in[24];
  const float* beq2= (const float*)d_in[25];
  const float* Wo1 = (const float*)d_in[26];
  const float* bo1 = (const float*)d_in[27];
  const float* Wo2 = (const float*)d_in[28];
  const float* bo2 = (const float*)d_in[29];
  float* out = (float*)d_out;
  float* ws = (float*)d_ws;

  float* GATES = ws;                       // 480
  float* STATS = ws + 480;                 // 1280: ST1(512) ST2(256) ST3(128)
                                           //       SQ1(256) SQ2(128)
  unsigned* SYNC = (unsigned*)(ws + 1760); // cnt, gen (zeroed by prep_k)
  float* SKIP = ws + 2048;                 // 4096*128
  float* BUF1 = SKIP + 4096*128;           // 4096*256 (z1)
  float* BUF2 = BUF1 + 4096*256;           // 4096*128 (z2, later zq1)
  float* BUF3 = BUF2 + 4096*128;           // 4096*64  (z3, later zq2)
  float* ZP   = BUF3 + 4096*64;            // 4096*12
  float* QOUT = ZP + 4096*12;              // 4096*18

  prep_k<<<1, dim3(256), 0, stream>>>(qw, GATES, STATS);

  PreArgs pa = { x, Wsk, bs, W1, b1, g1, be1, W2, b2, g2, be2,
                 W3, b3, g3, be3, Wp, bp,
                 STATS, SKIP, BUF1, BUF2, BUF3, ZP, SYNC };
  fused_pre<<<dim3(384), dim3(256), 0, stream>>>(pa);

  quantum_k<<<dim3(4096), dim3(256), 0, stream>>>(ZP, GATES, QOUT);

  PostArgs qa = { QOUT, Wq1, bq1, gq1, beq1, Wq2, bq2, gq2, beq2,
                  SKIP, Wo1, bo1, Wo2, bo2,
                  STATS, BUF2, BUF3, out, SYNC };
  fused_post<<<dim3(256), dim3(256), 0, stream>>>(qa);
}

// Round 10
// 446.581 us; speedup vs baseline: 1.9934x; 1.9934x over previous
//
#include <hip/hip_runtime.h>
#include <math.h>

#define LEAKY(v) ((v) > 0.f ? (v) : 0.01f * (v))

typedef float f2v __attribute__((ext_vector_type(2)));

// ------------------------------------------------------------------ prep ----
__device__ __forceinline__ void cmm2(const float* Ar, const float* Ai,
                                     const float* Br, const float* Bi,
                                     float* Cr, float* Ci) {
#pragma unroll
  for (int r = 0; r < 2; r++)
#pragma unroll
    for (int c = 0; c < 2; c++) {
      float xr = 0.f, xi = 0.f;
#pragma unroll
      for (int k = 0; k < 2; k++) {
        float ar = Ar[r*2+k], ai = Ai[r*2+k];
        float br = Br[k*2+c], bi = Bi[k*2+c];
        xr += ar*br - ai*bi;
        xi += ar*bi + ai*br;
      }
      Cr[r*2+c] = xr; Ci[r*2+c] = xi;
    }
}

// 60 fused 2x2 gates G = U3 @ RZ @ RY @ RX; zero the 1280 stats floats.
__global__ __launch_bounds__(256) void prep_k(const float* __restrict__ qw,
                                              float* __restrict__ gates,
                                              float* __restrict__ stats) {
  int t = threadIdx.x;
  for (int i = t; i < 1280; i += 256) stats[i] = 0.f;
  if (t < 60) {
    float a = qw[t*3+0], b = qw[t*3+1], c = qw[t*3+2];
    float ca = cosf(0.5f*a), sa = sinf(0.5f*a);
    float cb = cosf(0.5f*b), sb = sinf(0.5f*b);
    float RXr[4] = {ca, 0.f, 0.f, ca};
    float RXi[4] = {0.f, -sa, -sa, 0.f};
    float RYr[4] = {cb, -sb, sb, cb};
    float RYi[4] = {0.f, 0.f, 0.f, 0.f};
    float hc = 0.5f*c;
    float RZr[4] = {cosf(hc), 0.f, 0.f, cosf(hc)};
    float RZi[4] = {-sinf(hc), 0.f, 0.f, sinf(hc)};
    float epr = cosf(b), epi = sinf(b);
    float edr = cosf(c), edi = sinf(c);
    float eer = epr*edr - epi*edi, eei = epr*edi + epi*edr;
    float U3r[4] = {ca, -edr*sa, epr*sa, eer*ca};
    float U3i[4] = {0.f, -edi*sa, epi*sa, eei*ca};
    float T1r[4],T1i[4],T2r[4],T2i[4],Gr[4],Gi[4];
    cmm2(RYr,RYi, RXr,RXi, T1r,T1i);
    cmm2(RZr,RZi, T1r,T1i, T2r,T2i);
    cmm2(U3r,U3i, T2r,T2i, Gr,Gi);
#pragma unroll
    for (int m = 0; m < 4; m++) {
      gates[t*8 + 2*m]     = Gr[m];
      gates[t*8 + 2*m + 1] = Gi[m];
    }
  }
}

// ------------------------------------------------------- fused GEMM ----
// C[r][c] = sum_k pre(A)[r][k] * W[c][k] + bias[c]
// pre(A)[r][k] = f1(A1[r*ld1+k]) + scale2 * f2(A2[r*ld2+k])
//   fi(v) = stats_i ? leaky(sc_i[k]*v + sh_i[k]) : v
// statsOut: per-column (sum, sumsq) atomics.
// Tile 32x64 (grid.x = rows/32), register-prefetched K chunks for latency
// hiding at low block counts.
__device__ __forceinline__ void load_chunk(
    int tid, int r0, int c0, int kc, int K, int N,
    const float* __restrict__ A1, int ld1,
    const float* __restrict__ A2, int ld2, float scale2,
    bool lk1, bool lk2, const float* __restrict__ W,
    const float* sc1, const float* sh1,
    const float* sc2, const float* sh2,
    float* pa, float* pw) {
#pragma unroll
  for (int i = 0; i < 8; i++) {              // A tile: 32x64
    int t = tid + 256*i;
    int lr = t >> 6, lk = t & 63;
    int k = kc + lk;
    float av = 0.f;
    if (k < K) {
      float v1 = A1[(size_t)(r0+lr)*ld1 + k];
      v1 = sc1[k]*v1 + sh1[k];
      if (lk1) v1 = LEAKY(v1);
      av = v1;
      if (A2) {
        float v2 = A2[(size_t)(r0+lr)*ld2 + k];
        v2 = sc2[k]*v2 + sh2[k];
        if (lk2) v2 = LEAKY(v2);
        av += scale2 * v2;
      }
    }
    pa[i] = av;
  }
#pragma unroll
  for (int i = 0; i < 16; i++) {             // W tile: 64x64
    int t = tid + 256*i;
    int lr = t >> 6, lk = t & 63;
    int k = kc + lk;
    float wv = 0.f;
    if (k < K && c0 + lr < N) wv = W[(size_t)(c0+lr)*K + k];
    pw[i] = wv;
  }
}

__global__ __launch_bounds__(256) void gemm_f(
    const float* __restrict__ A1, const float* __restrict__ st1,
    const float* __restrict__ g1, const float* __restrict__ be1, int ld1,
    const float* __restrict__ A2, const float* __restrict__ st2,
    const float* __restrict__ g2, const float* __restrict__ be2, int ld2,
    float scale2,
    const float* __restrict__ W, const float* __restrict__ bias,
    float* __restrict__ C, float* __restrict__ statsOut, int N, int K) {
  __shared__ float As[32][65];
  __shared__ float Bs[64][65];
  __shared__ float sc1[256], sh1[256];
  __shared__ float sc2[128], sh2[128];
  const int r0 = blockIdx.x * 32;
  const int c0 = blockIdx.y * 64;
  const int tid = threadIdx.x;
  const int ty = tid >> 4, tx = tid & 15;    // ty 0..15 (2 rows), tx 0..15 (4 cols)
  const bool lk1 = (st1 != nullptr);
  const bool lk2 = (st2 != nullptr);
  for (int k = tid; k < K; k += 256) {
    if (lk1) {
      float mean = st1[2*k] * (1.f/4096.f);
      float var  = st1[2*k+1] * (1.f/4096.f) - mean*mean;
      float s = g1[k] * rsqrtf(var + 1e-5f);
      sc1[k] = s; sh1[k] = be1[k] - mean*s;
    } else { sc1[k] = 1.f; sh1[k] = 0.f; }
    if (A2 && k < 128) {
      if (lk2) {
        float mean = st2[2*k] * (1.f/4096.f);
        float var  = st2[2*k+1] * (1.f/4096.f) - mean*mean;
        float s = g2[k] * rsqrtf(var + 1e-5f);
        sc2[k] = s; sh2[k] = be2[k] - mean*s;
      } else { sc2[k] = 1.f; sh2[k] = 0.f; }
    }
  }
  __syncthreads();
  float acc[2][4] = {};
  float pa[8], pw[16];
  load_chunk(tid, r0, c0, 0, K, N, A1, ld1, A2, ld2, scale2,
             lk1, lk2, W, sc1, sh1, sc2, sh2, pa, pw);
  for (int kc = 0; kc < K; kc += 64) {
#pragma unroll
    for (int i = 0; i < 8; i++)  { int t = tid + 256*i; As[t>>6][t&63] = pa[i]; }
#pragma unroll
    for (int i = 0; i < 16; i++) { int t = tid + 256*i; Bs[t>>6][t&63] = pw[i]; }
    __syncthreads();
    if (kc + 64 < K)
      load_chunk(tid, r0, c0, kc + 64, K, N, A1, ld1, A2, ld2, scale2,
                 lk1, lk2, W, sc1, sh1, sc2, sh2, pa, pw);
#pragma unroll 16
    for (int kk = 0; kk < 64; kk++) {
      float ar[2], wr[4];
      ar[0] = As[ty*2][kk];
      ar[1] = As[ty*2+1][kk];
#pragma unroll
      for (int j = 0; j < 4; j++) wr[j] = Bs[tx*4+j][kk];
#pragma unroll
      for (int i = 0; i < 2; i++)
#pragma unroll
        for (int j = 0; j < 4; j++)
          acc[i][j] = fmaf(ar[i], wr[j], acc[i][j]);
    }
    __syncthreads();
  }
  float bv[4];
#pragma unroll
  for (int j = 0; j < 4; j++) {
    int c = c0 + tx*4 + j;
    bv[j] = (c < N) ? bias[c] : 0.f;
  }
#pragma unroll
  for (int i = 0; i < 2; i++) {
    int r = r0 + ty*2 + i;
#pragma unroll
    for (int j = 0; j < 4; j++) {
      int c = c0 + tx*4 + j;
      if (c < N) C[(size_t)r*N + c] = acc[i][j] + bv[j];
    }
  }
  if (statsOut) {
#pragma unroll
    for (int j = 0; j < 4; j++) {
      float s = 0.f, q = 0.f;
#pragma unroll
      for (int i = 0; i < 2; i++) {
        float v = acc[i][j] + bv[j];
        s += v; q += v*v;
      }
      As[ty][tx*4+j] = s;     // 16 x 64 partials
      Bs[ty][tx*4+j] = q;
    }
    __syncthreads();
    if (tid < 64) {
      float s = 0.f, q = 0.f;
#pragma unroll
      for (int t = 0; t < 16; t++) { s += As[t][tid]; q += Bs[t][tid]; }
      int c = c0 + tid;
      if (c < N) {
        atomicAdd(&statsOut[2*c], s);
        atomicAdd(&statsOut[2*c+1], q);
      }
    }
  }
}

// ----------------------------------------------------------- quantum sim ----
// (identical to round 4/7 — 238 us, VGPR 56, proven correct)
__device__ __forceinline__ int SWZi(int i) { return i ^ ((i >> 4) & 15); }
__device__ __forceinline__ int LINV_E(int i) {
  return i ^ ((i >> 1) & 0x7FF) ^ ((i & 1) ? 0xC00 : 0);
}
__device__ __forceinline__ int LINV_O(int i) {
  int hi = i & 0xAAA;
  return (i & 0x555) | ((hi ^ (hi << 6)) & 0xA80) | ((hi >> 6) & 0x2A);
}

template<int B>
__device__ __forceinline__ void gate16(f2v* a, const float* __restrict__ g) {
  const float g00r=g[0], g00i=g[1], g01r=g[2], g01i=g[3];
  const float g10r=g[4], g10i=g[5], g11r=g[6], g11i=g[7];
#pragma unroll
  for (int m = 0; m < 8; m++) {
    const int l0 = ((m >> B) << (B+1)) | (m & ((1<<B)-1));
    const int l1 = l0 | (1 << B);
    f2v A = a[l0], Bv = a[l1];
    f2v Ai; Ai.x = -A.y;  Ai.y = A.x;     // i*A
    f2v Bi; Bi.x = -Bv.y; Bi.y = Bv.x;    // i*B
    a[l0] = g00r*A + (g00i*Ai + (g01r*Bv + g01i*Bi));
    a[l1] = g10r*A + (g10i*Ai + (g11r*Bv + g11i*Bi));
  }
}

__global__ __launch_bounds__(256, 4) void quantum_k(const float* __restrict__ zpre,
                                                    const float* __restrict__ gates,
                                                    float* __restrict__ qout) {
  __shared__ f2v st[4096];                 // 32 KiB exactly
  float* stf = (float*)st;                 // aliased scratch (trig, reduction)
  const int tid = threadIdx.x, b = blockIdx.x;
  if (tid < 12) {
    float xp = tanhf(zpre[b*12 + tid]);
    float h = xp * 1.57079632679489662f;   // pi/2
    stf[tid] = cosf(h);
    stf[12 + tid] = sinf(h);
  }
  __syncthreads();
  float cs[12], sn[12];
#pragma unroll
  for (int q = 0; q < 12; q++) { cs[q] = stf[q]; sn[q] = stf[12+q]; }
  __syncthreads();                         // trig region reused by state below
  // Layout A: idx = (tid<<4)|l. idx bit bb <-> qubit 11-bb.
  f2v a[16];
  {
    float pre = 1.f;
#pragma unroll
    for (int q = 0; q < 8; q++) pre *= ((tid >> (7-q)) & 1) ? sn[q] : cs[q];
#pragma unroll
    for (int l = 0; l < 16; l++) {
      float v = pre;
      v *= (l & 8) ? sn[8]  : cs[8];
      v *= (l & 4) ? sn[9]  : cs[9];
      v *= (l & 2) ? sn[10] : cs[10];
      v *= (l & 1) ? sn[11] : cs[11];
      a[l].x = v; a[l].y = 0.f;
    }
  }
  // per-thread address bases (all accesses are base ^ const(l))
  const int mA    = tid & 15;
  const int baseA = (tid << 4) | mA;                 // layout A slots
  const int baseB = ((tid >> 4) << 8) | mA;          // layout B slots
  const int baseC = tid ^ ((tid >> 4) & 15);         // layout C slots
  const int gE    = SWZi(LINV_E(tid << 4));          // even-layer gather base
  const int gO    = SWZi(LINV_O(tid << 4));          // odd-layer gather base
  for (int layer = 0; layer < 5; layer++) {
    const float* gl = gates + layer * 96;
    gate16<3>(a, gl + 64); gate16<2>(a, gl + 72);    // qubits 8..11 (layout A)
    gate16<1>(a, gl + 80); gate16<0>(a, gl + 88);
#pragma unroll
    for (int l = 0; l < 16; l++) st[baseA ^ l] = a[l];
    __syncthreads();
#pragma unroll
    for (int l = 0; l < 16; l++) a[l] = st[baseB ^ ((l << 4) | l)];
    gate16<3>(a, gl + 32); gate16<2>(a, gl + 40);    // qubits 4..7 (layout B)
    gate16<1>(a, gl + 48); gate16<0>(a, gl + 56);
#pragma unroll
    for (int l = 0; l < 16; l++) st[baseB ^ ((l << 4) | l)] = a[l];
    __syncthreads();
#pragma unroll
    for (int l = 0; l < 16; l++) a[l] = st[baseC ^ (l << 8)];
    gate16<3>(a, gl +  0); gate16<2>(a, gl +  8);    // qubits 0..3 (layout C)
    gate16<1>(a, gl + 16); gate16<0>(a, gl + 24);
#pragma unroll
    for (int l = 0; l < 16; l++) st[baseC ^ (l << 8)] = a[l];
    __syncthreads();
    // CNOT chain: gather back to layout A, new[i] = old[Linv(i)]
    if ((layer & 1) == 0) {
#pragma unroll
      for (int l = 0; l < 16; l++) a[l] = st[gE ^ SWZi(LINV_E(l))];
    } else {
#pragma unroll
      for (int l = 0; l < 16; l++) a[l] = st[gO ^ SWZi(LINV_O(l))];
    }
    __syncthreads();
  }
  // Re-store post-CNOT state into layout-A slots for the X-measurement.
#pragma unroll
  for (int l = 0; l < 16; l++) st[baseA ^ l] = a[l];
  __syncthreads();
  // ---- measurement: 12 Z expectations + 6 X-type pair sums ----
  float pl[16], tot = 0.f;
#pragma unroll
  for (int l = 0; l < 16; l++) { pl[l] = a[l].x*a[l].x + a[l].y*a[l].y; tot += pl[l]; }
  float part[18];
#pragma unroll
  for (int q = 0; q < 8; q++) part[q] = ((tid >> (7-q)) & 1) ? -tot : tot;
#pragma unroll
  for (int q = 8; q < 12; q++) {
    const int bit = 11 - q;
    float s = 0.f;
#pragma unroll
    for (int l = 0; l < 16; l++) s += ((l >> bit) & 1) ? -pl[l] : pl[l];
    part[q] = s;
  }
#pragma unroll
  for (int q = 0; q < 6; q++) {
    const int bt = 7 - q;                  // qubit q <-> tid bit 7-q
    float s = 0.f;
    if (((tid >> bt) & 1) == 0) {
      const int tid2 = tid | (1 << bt);
      const int baseA2 = (tid2 << 4) | (tid2 & 15);
#pragma unroll
      for (int l = 0; l < 16; l++) {
        f2v bb = st[baseA2 ^ l];
        s += a[l].x*bb.x + a[l].y*bb.y;    // Re(conj(a0)*a1)
      }
    }
    part[12+q] = 2.f * s;
  }
  __syncthreads();                         // st reads done; reuse as scratch
#pragma unroll
  for (int j = 0; j < 18; j++) {
    float v = part[j];
#pragma unroll
    for (int m = 1; m < 64; m <<= 1) v += __shfl_xor(v, m);
    if ((tid & 63) == 0) stf[(tid >> 6)*18 + j] = v;
  }
  __syncthreads();
  if (tid < 18) qout[b*18 + tid] = stf[tid] + stf[18+tid] + stf[36+tid] + stf[54+tid];
}

// ---------------------------------------------------------------- final ----
// out[r] = leaky( leakyBN(P2_r) @ Wo1^T + bo1 ) @ Wo2^T + bo2
__global__ __launch_bounds__(256) void final_k(const float* __restrict__ P2,
                                               const float* __restrict__ stats,
                                               const float* __restrict__ g,
                                               const float* __restrict__ be,
                                               const float* __restrict__ Wo1,
                                               const float* __restrict__ bo1,
                                               const float* __restrict__ Wo2,
                                               const float* __restrict__ bo2,
                                               float* __restrict__ out) {
  __shared__ float sc[64], sh[64];
  int tid = threadIdx.x;
  if (tid < 64) {
    float mean = stats[2*tid] * (1.f/4096.f);
    float var  = stats[2*tid+1] * (1.f/4096.f) - mean*mean;
    float s = g[tid] * rsqrtf(var + 1e-5f);
    sc[tid] = s; sh[tid] = be[tid] - mean*s;
  }
  __syncthreads();
  int row = blockIdx.x*8 + (tid >> 5);
  int o = tid & 31;
  float acc = 0.f;
#pragma unroll 8
  for (int k = 0; k < 64; k++) {
    float v = sc[k]*P2[(size_t)row*64 + k] + sh[k];
    v = LEAKY(v);
    acc = fmaf(v, Wo1[o*64 + k], acc);
  }
  float h = acc + bo1[o];
  h = LEAKY(h);
  float v = h * Wo2[o];
#pragma unroll
  for (int m = 1; m < 32; m <<= 1) v += __shfl_xor(v, m);
  if (o == 0) out[row] = v + bo2[0];
}

// --------------------------------------------------------------- launch ----
extern "C" void kernel_launch(void* const* d_in, const int* in_sizes, int n_in,
                              void* d_out, int out_size, void* d_ws, size_t ws_size,
                              hipStream_t stream) {
  (void)in_sizes; (void)n_in; (void)out_size; (void)ws_size;
  const float* x   = (const float*)d_in[0];
  const float* Wsk = (const float*)d_in[1];
  const float* bs  = (const float*)d_in[2];
  const float* W1  = (const float*)d_in[3];
  const float* b1  = (const float*)d_in[4];
  const float* g1  = (const float*)d_in[5];
  const float* be1 = (const float*)d_in[6];
  const float* W2  = (const float*)d_in[7];
  const float* b2  = (const float*)d_in[8];
  const float* g2  = (const float*)d_in[9];
  const float* be2 = (const float*)d_in[10];
  const float* W3  = (const float*)d_in[11];
  const float* b3  = (const float*)d_in[12];
  const float* g3  = (const float*)d_in[13];
  const float* be3 = (const float*)d_in[14];
  const float* Wp  = (const float*)d_in[15];
  const float* bp  = (const float*)d_in[16];
  const float* qw  = (const float*)d_in[17];
  const float* Wq1 = (const float*)d_in[18];
  const float* bq1 = (const float*)d_in[19];
  const float* gq1 = (const float*)d_in[20];
  const float* beq1= (const float*)d_in[21];
  const float* Wq2 = (const float*)d_in[22];
  const float* bq2 = (const float*)d_in[23];
  const float* gq2 = (const float*)d_in[24];
  const float* beq2= (const float*)d_in[25];
  const float* Wo1 = (const float*)d_in[26];
  const float* bo1 = (const float*)d_in[27];
  const float* Wo2 = (const float*)d_in[28];
  const float* bo2 = (const float*)d_in[29];
  float* out = (float*)d_out;
  float* ws = (float*)d_ws;

  float* GATES = ws;                       // 480
  float* ST1 = ws + 480;                   // 512 |
  float* ST2 = ST1 + 512;                  // 256 | contiguous 1280 floats,
  float* ST3 = ST2 + 256;                  // 128 | zeroed by prep_k
  float* SQ1 = ST3 + 128;                  // 256 |
  float* SQ2 = SQ1 + 256;                  // 128 |
  float* SKIP = ws + 2048;                 // 4096*128
  float* BUF1 = SKIP + 4096*128;           // 4096*256 (z1)
  float* BUF2 = BUF1 + 4096*256;           // 4096*128 (z2, later zq1)
  float* BUF3 = BUF2 + 4096*128;           // 4096*64  (z3, later zq2)
  float* ZP   = BUF3 + 4096*64;            // 4096*12
  float* QOUT = ZP + 4096*12;              // 4096*18

  dim3 blk(256);
  prep_k<<<1, blk, 0, stream>>>(qw, GATES, ST1);
  // skip = x @ Ws^T + bs
  gemm_f<<<dim3(128,2), blk, 0, stream>>>(x, nullptr,nullptr,nullptr, 64,
      nullptr,nullptr,nullptr,nullptr, 0, 0.f, Wsk, bs, SKIP, nullptr, 128, 64);
  // z1 = x @ W1^T + b1, stats -> ST1
  gemm_f<<<dim3(128,4), blk, 0, stream>>>(x, nullptr,nullptr,nullptr, 64,
      nullptr,nullptr,nullptr,nullptr, 0, 0.f, W1, b1, BUF1, ST1, 256, 64);
  // z2 = leakyBN1(z1) @ W2^T + b2, stats -> ST2
  gemm_f<<<dim3(128,2), blk, 0, stream>>>(BUF1, ST1, g1, be1, 256,
      nullptr,nullptr,nullptr,nullptr, 0, 0.f, W2, b2, BUF2, ST2, 128, 256);
  // z3 = leakyBN2(z2) @ W3^T + b3, stats -> ST3
  gemm_f<<<dim3(128,1), blk, 0, stream>>>(BUF2, ST2, g2, be2, 128,
      nullptr,nullptr,nullptr,nullptr, 0, 0.f, W3, b3, BUF3, ST3, 64, 128);
  // zp = (leakyBN3(z3) + 0.1*leakyBN1(z1[:, :64])) @ Wp^T + bp
  gemm_f<<<dim3(128,1), blk, 0, stream>>>(BUF3, ST3, g3, be3, 64,
      BUF1, ST1, g1, be1, 256, 0.1f, Wp, bp, ZP, nullptr, 12, 64);
  // quantum (applies tanh internally)
  quantum_k<<<dim3(4096), blk, 0, stream>>>(ZP, GATES, QOUT);
  // zq1 = q_out @ Wq1^T + bq1, stats -> SQ1
  gemm_f<<<dim3(128,2), blk, 0, stream>>>(QOUT, nullptr,nullptr,nullptr, 18,
      nullptr,nullptr,nullptr,nullptr, 0, 0.f, Wq1, bq1, BUF2, SQ1, 128, 18);
  // zq2 = (leakyBNq1(zq1) + skip) @ Wq2^T + bq2, stats -> SQ2
  gemm_f<<<dim3(128,1), blk, 0, stream>>>(BUF2, SQ1, gq1, beq1, 128,
      SKIP, nullptr, nullptr, nullptr, 128, 1.0f, Wq2, bq2, BUF3, SQ2, 64, 128);
  // out = leaky(leakyBNq2(zq2) @ Wo1^T + bo1) @ Wo2^T + bo2
  final_k<<<dim3(512), blk, 0, stream>>>(BUF3, SQ2, gq2, beq2, Wo1, bo1, Wo2, bo2, out);
}

// Round 11
// 427.047 us; speedup vs baseline: 2.0846x; 1.0457x over previous
//
#include <hip/hip_runtime.h>
#include <math.h>

#define LEAKY(v) ((v) > 0.f ? (v) : 0.01f * (v))

typedef float f2v __attribute__((ext_vector_type(2)));

// ------------------------------------------------------------------ prep ----
__device__ __forceinline__ void cmm2(const float* Ar, const float* Ai,
                                     const float* Br, const float* Bi,
                                     float* Cr, float* Ci) {
#pragma unroll
  for (int r = 0; r < 2; r++)
#pragma unroll
    for (int c = 0; c < 2; c++) {
      float xr = 0.f, xi = 0.f;
#pragma unroll
      for (int k = 0; k < 2; k++) {
        float ar = Ar[r*2+k], ai = Ai[r*2+k];
        float br = Br[k*2+c], bi = Bi[k*2+c];
        xr += ar*br - ai*bi;
        xi += ar*bi + ai*br;
      }
      Cr[r*2+c] = xr; Ci[r*2+c] = xi;
    }
}

// 60 fused 2x2 gates G = U3 @ RZ @ RY @ RX; zero the 1280 stats floats.
__global__ __launch_bounds__(256) void prep_k(const float* __restrict__ qw,
                                              float* __restrict__ gates,
                                              float* __restrict__ stats) {
  int t = threadIdx.x;
  for (int i = t; i < 1280; i += 256) stats[i] = 0.f;
  if (t < 60) {
    float a = qw[t*3+0], b = qw[t*3+1], c = qw[t*3+2];
    float ca = cosf(0.5f*a), sa = sinf(0.5f*a);
    float cb = cosf(0.5f*b), sb = sinf(0.5f*b);
    float RXr[4] = {ca, 0.f, 0.f, ca};
    float RXi[4] = {0.f, -sa, -sa, 0.f};
    float RYr[4] = {cb, -sb, sb, cb};
    float RYi[4] = {0.f, 0.f, 0.f, 0.f};
    float hc = 0.5f*c;
    float RZr[4] = {cosf(hc), 0.f, 0.f, cosf(hc)};
    float RZi[4] = {-sinf(hc), 0.f, 0.f, sinf(hc)};
    float epr = cosf(b), epi = sinf(b);
    float edr = cosf(c), edi = sinf(c);
    float eer = epr*edr - epi*edi, eei = epr*edi + epi*edr;
    float U3r[4] = {ca, -edr*sa, epr*sa, eer*ca};
    float U3i[4] = {0.f, -edi*sa, epi*sa, eei*ca};
    float T1r[4],T1i[4],T2r[4],T2i[4],Gr[4],Gi[4];
    cmm2(RYr,RYi, RXr,RXi, T1r,T1i);
    cmm2(RZr,RZi, T1r,T1i, T2r,T2i);
    cmm2(U3r,U3i, T2r,T2i, Gr,Gi);
#pragma unroll
    for (int m = 0; m < 4; m++) {
      gates[t*8 + 2*m]     = Gr[m];
      gates[t*8 + 2*m + 1] = Gi[m];
    }
  }
}

// ------------------------------------------------------- gemm body (device) ----
struct GemmLds {
  float As[32][65];
  float Bs[64][65];
  float sc1[256], sh1[256];
  float sc2[128], sh2[128];
};

__device__ __forceinline__ void load_chunk(
    int tid, int r0, int c0, int kc, int K, int N,
    const float* __restrict__ A1, int ld1,
    const float* __restrict__ A2, int ld2, float scale2,
    bool lk1, bool lk2, const float* __restrict__ W,
    const float* sc1, const float* sh1,
    const float* sc2, const float* sh2,
    float* pa, float* pw) {
#pragma unroll
  for (int i = 0; i < 8; i++) {              // A tile: 32x64
    int t = tid + 256*i;
    int lr = t >> 6, lk = t & 63;
    int k = kc + lk;
    float av = 0.f;
    if (k < K) {
      float v1 = A1[(size_t)(r0+lr)*ld1 + k];
      v1 = sc1[k]*v1 + sh1[k];
      if (lk1) v1 = LEAKY(v1);
      av = v1;
      if (A2) {
        float v2 = A2[(size_t)(r0+lr)*ld2 + k];
        v2 = sc2[k]*v2 + sh2[k];
        if (lk2) v2 = LEAKY(v2);
        av += scale2 * v2;
      }
    }
    pa[i] = av;
  }
#pragma unroll
  for (int i = 0; i < 16; i++) {             // W tile: 64x64
    int t = tid + 256*i;
    int lr = t >> 6, lk = t & 63;
    int k = kc + lk;
    float wv = 0.f;
    if (k < K && c0 + lr < N) wv = W[(size_t)(c0+lr)*K + k];
    pw[i] = wv;
  }
}

// Tile 32x64 at (bx,by); register-prefetched K chunks (r10-proven body).
__device__ __forceinline__ void gemm_body(
    GemmLds& L, int bx, int by,
    const float* __restrict__ A1, const float* __restrict__ st1,
    const float* __restrict__ g1, const float* __restrict__ be1, int ld1,
    const float* __restrict__ A2, const float* __restrict__ st2,
    const float* __restrict__ g2, const float* __restrict__ be2, int ld2,
    float scale2,
    const float* __restrict__ W, const float* __restrict__ bias,
    float* __restrict__ C, float* __restrict__ statsOut, int N, int K) {
  const int r0 = bx * 32;
  const int c0 = by * 64;
  const int tid = threadIdx.x;
  const int ty = tid >> 4, tx = tid & 15;
  const bool lk1 = (st1 != nullptr);
  const bool lk2 = (st2 != nullptr);
  for (int k = tid; k < K; k += 256) {
    if (lk1) {
      float mean = st1[2*k] * (1.f/4096.f);
      float var  = st1[2*k+1] * (1.f/4096.f) - mean*mean;
      float s = g1[k] * rsqrtf(var + 1e-5f);
      L.sc1[k] = s; L.sh1[k] = be1[k] - mean*s;
    } else { L.sc1[k] = 1.f; L.sh1[k] = 0.f; }
    if (A2 && k < 128) {
      if (lk2) {
        float mean = st2[2*k] * (1.f/4096.f);
        float var  = st2[2*k+1] * (1.f/4096.f) - mean*mean;
        float s = g2[k] * rsqrtf(var + 1e-5f);
        L.sc2[k] = s; L.sh2[k] = be2[k] - mean*s;
      } else { L.sc2[k] = 1.f; L.sh2[k] = 0.f; }
    }
  }
  __syncthreads();
  float acc[2][4] = {};
  float pa[8], pw[16];
  load_chunk(tid, r0, c0, 0, K, N, A1, ld1, A2, ld2, scale2,
             lk1, lk2, W, L.sc1, L.sh1, L.sc2, L.sh2, pa, pw);
  for (int kc = 0; kc < K; kc += 64) {
#pragma unroll
    for (int i = 0; i < 8; i++)  { int t = tid + 256*i; L.As[t>>6][t&63] = pa[i]; }
#pragma unroll
    for (int i = 0; i < 16; i++) { int t = tid + 256*i; L.Bs[t>>6][t&63] = pw[i]; }
    __syncthreads();
    if (kc + 64 < K)
      load_chunk(tid, r0, c0, kc + 64, K, N, A1, ld1, A2, ld2, scale2,
                 lk1, lk2, W, L.sc1, L.sh1, L.sc2, L.sh2, pa, pw);
#pragma unroll 16
    for (int kk = 0; kk < 64; kk++) {
      float ar[2], wr[4];
      ar[0] = L.As[ty*2][kk];
      ar[1] = L.As[ty*2+1][kk];
#pragma unroll
      for (int j = 0; j < 4; j++) wr[j] = L.Bs[tx*4+j][kk];
#pragma unroll
      for (int i = 0; i < 2; i++)
#pragma unroll
        for (int j = 0; j < 4; j++)
          acc[i][j] = fmaf(ar[i], wr[j], acc[i][j]);
    }
    __syncthreads();
  }
  float bv[4];
#pragma unroll
  for (int j = 0; j < 4; j++) {
    int c = c0 + tx*4 + j;
    bv[j] = (c < N) ? bias[c] : 0.f;
  }
#pragma unroll
  for (int i = 0; i < 2; i++) {
    int r = r0 + ty*2 + i;
#pragma unroll
    for (int j = 0; j < 4; j++) {
      int c = c0 + tx*4 + j;
      if (c < N) C[(size_t)r*N + c] = acc[i][j] + bv[j];
    }
  }
  if (statsOut) {
#pragma unroll
    for (int j = 0; j < 4; j++) {
      float s = 0.f, q = 0.f;
#pragma unroll
      for (int i = 0; i < 2; i++) {
        float v = acc[i][j] + bv[j];
        s += v; q += v*v;
      }
      L.As[ty][tx*4+j] = s;
      L.Bs[ty][tx*4+j] = q;
    }
    __syncthreads();
    if (tid < 64) {
      float s = 0.f, q = 0.f;
#pragma unroll
      for (int t = 0; t < 16; t++) { s += L.As[t][tid]; q += L.Bs[t][tid]; }
      int c = c0 + tid;
      if (c < N) {
        atomicAdd(&statsOut[2*c], s);
        atomicAdd(&statsOut[2*c+1], q);
      }
    }
  }
}

__global__ __launch_bounds__(256) void gemm_f(
    const float* __restrict__ A1, const float* __restrict__ st1,
    const float* __restrict__ g1, const float* __restrict__ be1, int ld1,
    const float* __restrict__ A2, const float* __restrict__ st2,
    const float* __restrict__ g2, const float* __restrict__ be2, int ld2,
    float scale2,
    const float* __restrict__ W, const float* __restrict__ bias,
    float* __restrict__ C, float* __restrict__ statsOut, int N, int K) {
  __shared__ GemmLds L;
  gemm_body(L, blockIdx.x, blockIdx.y, A1, st1, g1, be1, ld1,
            A2, st2, g2, be2, ld2, scale2, W, bias, C, statsOut, N, K);
}

// z1 (y<4) and skip (y>=4) in one dispatch — both read only x.
__global__ __launch_bounds__(256) void z1skip_k(
    const float* __restrict__ x,
    const float* __restrict__ W1, const float* __restrict__ b1,
    float* __restrict__ BUF1, float* __restrict__ ST1,
    const float* __restrict__ Wsk, const float* __restrict__ bs,
    float* __restrict__ SKIP) {
  __shared__ GemmLds L;
  if (blockIdx.y < 4)
    gemm_body(L, blockIdx.x, blockIdx.y, x, nullptr,nullptr,nullptr, 64,
              nullptr,nullptr,nullptr,nullptr, 0, 0.f,
              W1, b1, BUF1, ST1, 256, 64);
  else
    gemm_body(L, blockIdx.x, blockIdx.y - 4, x, nullptr,nullptr,nullptr, 64,
              nullptr,nullptr,nullptr,nullptr, 0, 0.f,
              Wsk, bs, SKIP, nullptr, 128, 64);
}

// ----------------------------------------------------------- quantum sim ----
// Round-10 quantum_k + fused zp prologue (computes its own row's
// zp = (leakyBN3(z3)+0.1*leakyBN1(z1[:, :64]))@Wp^T+bp, then tanh+trig).
__device__ __forceinline__ int SWZi(int i) { return i ^ ((i >> 4) & 15); }
__device__ __forceinline__ int LINV_E(int i) {
  return i ^ ((i >> 1) & 0x7FF) ^ ((i & 1) ? 0xC00 : 0);
}
__device__ __forceinline__ int LINV_O(int i) {
  int hi = i & 0xAAA;
  return (i & 0x555) | ((hi ^ (hi << 6)) & 0xA80) | ((hi >> 6) & 0x2A);
}

template<int B>
__device__ __forceinline__ void gate16(f2v* a, const float* __restrict__ g) {
  const float g00r=g[0], g00i=g[1], g01r=g[2], g01i=g[3];
  const float g10r=g[4], g10i=g[5], g11r=g[6], g11i=g[7];
#pragma unroll
  for (int m = 0; m < 8; m++) {
    const int l0 = ((m >> B) << (B+1)) | (m & ((1<<B)-1));
    const int l1 = l0 | (1 << B);
    f2v A = a[l0], Bv = a[l1];
    f2v Ai; Ai.x = -A.y;  Ai.y = A.x;     // i*A
    f2v Bi; Bi.x = -Bv.y; Bi.y = Bv.x;    // i*B
    a[l0] = g00r*A + (g00i*Ai + (g01r*Bv + g01i*Bi));
    a[l1] = g10r*A + (g10i*Ai + (g11r*Bv + g11i*Bi));
  }
}

__global__ __launch_bounds__(256, 4) void quantum_k(
    const float* __restrict__ z3buf,   // BUF3: 4096 x 64
    const float* __restrict__ z1buf,   // BUF1: 4096 x 256
    const float* __restrict__ stats,   // ST1 at +0, ST3 at +768
    const float* __restrict__ g1, const float* __restrict__ be1,
    const float* __restrict__ g3, const float* __restrict__ be3,
    const float* __restrict__ Wp, const float* __restrict__ bp,
    const float* __restrict__ gates,
    float* __restrict__ qout) {
  __shared__ f2v st[4096];                 // 32 KiB exactly
  float* stf = (float*)st;                 // aliased scratch
  const int tid = threadIdx.x, b = blockIdx.x;
  // ---- zp prologue: sc/sh for BN3 and BN1[0:64] ----
  if (tid < 64) {
    const float* ST3 = stats + 768;
    float mean = ST3[2*tid] * (1.f/4096.f);
    float var  = ST3[2*tid+1] * (1.f/4096.f) - mean*mean;
    float s = g3[tid] * rsqrtf(var + 1e-5f);
    stf[tid] = s; stf[64+tid] = be3[tid] - mean*s;
  } else if (tid < 128) {
    int k = tid - 64;
    float mean = stats[2*k] * (1.f/4096.f);
    float var  = stats[2*k+1] * (1.f/4096.f) - mean*mean;
    float s = g1[k] * rsqrtf(var + 1e-5f);
    stf[128+k] = s; stf[192+k] = be1[k] - mean*s;
  }
  __syncthreads();
  if (tid < 64) {
    int k = tid;
    float v3 = stf[k]*z3buf[(size_t)b*64 + k] + stf[64+k];
    v3 = LEAKY(v3);
    float v1 = stf[128+k]*z1buf[(size_t)b*256 + k] + stf[192+k];
    v1 = LEAKY(v1);
    stf[256+k] = v3 + 0.1f*v1;
  }
  __syncthreads();
  if (tid < 12) {
    float acc = bp[tid];
#pragma unroll 8
    for (int k = 0; k < 64; k++) acc = fmaf(stf[256+k], Wp[tid*64+k], acc);
    float xp = tanhf(acc);
    float h = xp * 1.57079632679489662f;   // pi/2
    stf[320+tid] = cosf(h);
    stf[332+tid] = sinf(h);
  }
  __syncthreads();
  float cs[12], sn[12];
#pragma unroll
  for (int q = 0; q < 12; q++) { cs[q] = stf[320+q]; sn[q] = stf[332+q]; }
  __syncthreads();                         // scratch region reused by state
  // Layout A: idx = (tid<<4)|l. idx bit bb <-> qubit 11-bb.
  f2v a[16];
  {
    float pre = 1.f;
#pragma unroll
    for (int q = 0; q < 8; q++) pre *= ((tid >> (7-q)) & 1) ? sn[q] : cs[q];
#pragma unroll
    for (int l = 0; l < 16; l++) {
      float v = pre;
      v *= (l & 8) ? sn[8]  : cs[8];
      v *= (l & 4) ? sn[9]  : cs[9];
      v *= (l & 2) ? sn[10] : cs[10];
      v *= (l & 1) ? sn[11] : cs[11];
      a[l].x = v; a[l].y = 0.f;
    }
  }
  // per-thread address bases (all accesses are base ^ const(l))
  const int mA    = tid & 15;
  const int baseA = (tid << 4) | mA;                 // layout A slots
  const int baseB = ((tid >> 4) << 8) | mA;          // layout B slots
  const int baseC = tid ^ ((tid >> 4) & 15);         // layout C slots
  const int gE    = SWZi(LINV_E(tid << 4));          // even-layer gather base
  const int gO    = SWZi(LINV_O(tid << 4));          // odd-layer gather base
  for (int layer = 0; layer < 5; layer++) {
    const float* gl = gates + layer * 96;
    gate16<3>(a, gl + 64); gate16<2>(a, gl + 72);    // qubits 8..11 (layout A)
    gate16<1>(a, gl + 80); gate16<0>(a, gl + 88);
#pragma unroll
    for (int l = 0; l < 16; l++) st[baseA ^ l] = a[l];
    __syncthreads();
#pragma unroll
    for (int l = 0; l < 16; l++) a[l] = st[baseB ^ ((l << 4) | l)];
    gate16<3>(a, gl + 32); gate16<2>(a, gl + 40);    // qubits 4..7 (layout B)
    gate16<1>(a, gl + 48); gate16<0>(a, gl + 56);
#pragma unroll
    for (int l = 0; l < 16; l++) st[baseB ^ ((l << 4) | l)] = a[l];
    __syncthreads();
#pragma unroll
    for (int l = 0; l < 16; l++) a[l] = st[baseC ^ (l << 8)];
    gate16<3>(a, gl +  0); gate16<2>(a, gl +  8);    // qubits 0..3 (layout C)
    gate16<1>(a, gl + 16); gate16<0>(a, gl + 24);
#pragma unroll
    for (int l = 0; l < 16; l++) st[baseC ^ (l << 8)] = a[l];
    __syncthreads();
    // CNOT chain: gather back to layout A, new[i] = old[Linv(i)]
    if ((layer & 1) == 0) {
#pragma unroll
      for (int l = 0; l < 16; l++) a[l] = st[gE ^ SWZi(LINV_E(l))];
    } else {
#pragma unroll
      for (int l = 0; l < 16; l++) a[l] = st[gO ^ SWZi(LINV_O(l))];
    }
    __syncthreads();
  }
  // Re-store post-CNOT state into layout-A slots for the X-measurement.
#pragma unroll
  for (int l = 0; l < 16; l++) st[baseA ^ l] = a[l];
  __syncthreads();
  // ---- measurement: 12 Z expectations + 6 X-type pair sums ----
  float pl[16], tot = 0.f;
#pragma unroll
  for (int l = 0; l < 16; l++) { pl[l] = a[l].x*a[l].x + a[l].y*a[l].y; tot += pl[l]; }
  float part[18];
#pragma unroll
  for (int q = 0; q < 8; q++) part[q] = ((tid >> (7-q)) & 1) ? -tot : tot;
#pragma unroll
  for (int q = 8; q < 12; q++) {
    const int bit = 11 - q;
    float s = 0.f;
#pragma unroll
    for (int l = 0; l < 16; l++) s += ((l >> bit) & 1) ? -pl[l] : pl[l];
    part[q] = s;
  }
#pragma unroll
  for (int q = 0; q < 6; q++) {
    const int bt = 7 - q;                  // qubit q <-> tid bit 7-q
    float s = 0.f;
    if (((tid >> bt) & 1) == 0) {
      const int tid2 = tid | (1 << bt);
      const int baseA2 = (tid2 << 4) | (tid2 & 15);
#pragma unroll
      for (int l = 0; l < 16; l++) {
        f2v bb = st[baseA2 ^ l];
        s += a[l].x*bb.x + a[l].y*bb.y;    // Re(conj(a0)*a1)
      }
    }
    part[12+q] = 2.f * s;
  }
  __syncthreads();                         // st reads done; reuse as scratch
#pragma unroll
  for (int j = 0; j < 18; j++) {
    float v = part[j];
#pragma unroll
    for (int m = 1; m < 64; m <<= 1) v += __shfl_xor(v, m);
    if ((tid & 63) == 0) stf[(tid >> 6)*18 + j] = v;
  }
  __syncthreads();
  if (tid < 18) qout[b*18 + tid] = stf[tid] + stf[18+tid] + stf[36+tid] + stf[54+tid];
}

// ---------------------------------------------------------------- final ----
__global__ __launch_bounds__(256) void final_k(const float* __restrict__ P2,
                                               const float* __restrict__ stats,
                                               const float* __restrict__ g,
                                               const float* __restrict__ be,
                                               const float* __restrict__ Wo1,
                                               const float* __restrict__ bo1,
                                               const float* __restrict__ Wo2,
                                               const float* __restrict__ bo2,
                                               float* __restrict__ out) {
  __shared__ float sc[64], sh[64];
  int tid = threadIdx.x;
  if (tid < 64) {
    float mean = stats[2*tid] * (1.f/4096.f);
    float var  = stats[2*tid+1] * (1.f/4096.f) - mean*mean;
    float s = g[tid] * rsqrtf(var + 1e-5f);
    sc[tid] = s; sh[tid] = be[tid] - mean*s;
  }
  __syncthreads();
  int row = blockIdx.x*8 + (tid >> 5);
  int o = tid & 31;
  float acc = 0.f;
#pragma unroll 8
  for (int k = 0; k < 64; k++) {
    float v = sc[k]*P2[(size_t)row*64 + k] + sh[k];
    v = LEAKY(v);
    acc = fmaf(v, Wo1[o*64 + k], acc);
  }
  float h = acc + bo1[o];
  h = LEAKY(h);
  float v = h * Wo2[o];
#pragma unroll
  for (int m = 1; m < 32; m <<= 1) v += __shfl_xor(v, m);
  if (o == 0) out[row] = v + bo2[0];
}

// --------------------------------------------------------------- launch ----
extern "C" void kernel_launch(void* const* d_in, const int* in_sizes, int n_in,
                              void* d_out, int out_size, void* d_ws, size_t ws_size,
                              hipStream_t stream) {
  (void)in_sizes; (void)n_in; (void)out_size; (void)ws_size;
  const float* x   = (const float*)d_in[0];
  const float* Wsk = (const float*)d_in[1];
  const float* bs  = (const float*)d_in[2];
  const float* W1  = (const float*)d_in[3];
  const float* b1  = (const float*)d_in[4];
  const float* g1  = (const float*)d_in[5];
  const float* be1 = (const float*)d_in[6];
  const float* W2  = (const float*)d_in[7];
  const float* b2  = (const float*)d_in[8];
  const float* g2  = (const float*)d_in[9];
  const float* be2 = (const float*)d_in[10];
  const float* W3  = (const float*)d_in[11];
  const float* b3  = (const float*)d_in[12];
  const float* g3  = (const float*)d_in[13];
  const float* be3 = (const float*)d_in[14];
  const float* Wp  = (const float*)d_in[15];
  const float* bp  = (const float*)d_in[16];
  const float* qw  = (const float*)d_in[17];
  const float* Wq1 = (const float*)d_in[18];
  const float* bq1 = (const float*)d_in[19];
  const float* gq1 = (const float*)d_in[20];
  const float* beq1= (const float*)d_in[21];
  const float* Wq2 = (const float*)d_in[22];
  const float* bq2 = (const float*)d_in[23];
  const float* gq2 = (const float*)d_in[24];
  const float* beq2= (const float*)d_in[25];
  const float* Wo1 = (const float*)d_in[26];
  const float* bo1 = (const float*)d_in[27];
  const float* Wo2 = (const float*)d_in[28];
  const float* bo2 = (const float*)d_in[29];
  float* out = (float*)d_out;
  float* ws = (float*)d_ws;

  float* GATES = ws;                       // 480
  float* STATS = ws + 480;                 // 1280: ST1(512) ST2(256) ST3(128)
                                           //       SQ1(256) SQ2(128)
  float* ST1 = STATS;
  float* ST2 = STATS + 512;
  float* ST3 = STATS + 768;
  float* SQ1 = STATS + 896;
  float* SQ2 = STATS + 1152;
  float* SKIP = ws + 2048;                 // 4096*128
  float* BUF1 = SKIP + 4096*128;           // 4096*256 (z1)
  float* BUF2 = BUF1 + 4096*256;           // 4096*128 (z2, later zq1)
  float* BUF3 = BUF2 + 4096*128;           // 4096*64  (z3, later zq2)
  float* QOUT = BUF3 + 4096*64 + 4096*12;  // 4096*18

  dim3 blk(256);
  prep_k<<<1, blk, 0, stream>>>(qw, GATES, STATS);
  // z1 (stats -> ST1) + skip, one dispatch
  z1skip_k<<<dim3(128,6), blk, 0, stream>>>(x, W1, b1, BUF1, ST1, Wsk, bs, SKIP);
  // z2 = leakyBN1(z1) @ W2^T + b2, stats -> ST2
  gemm_f<<<dim3(128,2), blk, 0, stream>>>(BUF1, ST1, g1, be1, 256,
      nullptr,nullptr,nullptr,nullptr, 0, 0.f, W2, b2, BUF2, ST2, 128, 256);
  // z3 = leakyBN2(z2) @ W3^T + b3, stats -> ST3
  gemm_f<<<dim3(128,1), blk, 0, stream>>>(BUF2, ST2, g2, be2, 128,
      nullptr,nullptr,nullptr,nullptr, 0, 0.f, W3, b3, BUF3, ST3, 64, 128);
  // quantum (computes zp + tanh internally from z3/z1 + stats)
  quantum_k<<<dim3(4096), blk, 0, stream>>>(BUF3, BUF1, STATS,
      g1, be1, g3, be3, Wp, bp, GATES, QOUT);
  // zq1 = q_out @ Wq1^T + bq1, stats -> SQ1
  gemm_f<<<dim3(128,2), blk, 0, stream>>>(QOUT, nullptr,nullptr,nullptr, 18,
      nullptr,nullptr,nullptr,nullptr, 0, 0.f, Wq1, bq1, BUF2, SQ1, 128, 18);
  // zq2 = (leakyBNq1(zq1) + skip) @ Wq2^T + bq2, stats -> SQ2
  gemm_f<<<dim3(128,1), blk, 0, stream>>>(BUF2, SQ1, gq1, beq1, 128,
      SKIP, nullptr, nullptr, nullptr, 128, 1.0f, Wq2, bq2, BUF3, SQ2, 64, 128);
  // out = leaky(leakyBNq2(zq2) @ Wo1^T + bo1) @ Wo2^T + bo2
  final_k<<<dim3(512), blk, 0, stream>>>(BUF3, SQ2, gq2, beq2, Wo1, bo1, Wo2, bo2, out);
}